// Round 14
// baseline (108.706 us; speedup 1.0000x reference)
//
#include <hip/hip_runtime.h>
#include <hip/hip_bf16.h>
#include <stdint.h>

// Problem constants (CompressedKVAttention_11708080848911)
#define Bc    4
#define Hc    32
#define HKVc  8
#define QLc   16
#define KVc   8192
#define Dc    128
#define NREPc 4   // H / HKV

typedef _Float16 f16x8 __attribute__((ext_vector_type(8)));
typedef _Float16 f16x4 __attribute__((ext_vector_type(4)));
typedef float f32x4  __attribute__((ext_vector_type(4)));
typedef int   i32x4  __attribute__((ext_vector_type(4)));
typedef uint32_t u32x2 __attribute__((ext_vector_type(2)));

// Pack two sign-extended-int8 dwords into one half2 = (x0+1152, x1+1152).
// fp16 0x6400|u = 1024+u (u in [0,255] exact); u = byte^0x80 = x+128.
__device__ __forceinline__ uint32_t pk1152(int x0, int x1) {
  return (__builtin_amdgcn_perm((uint32_t)x1, (uint32_t)x0, 0x05040100u)
          & 0x00FF00FFu) ^ 0x64806480u;
}

// Raw barrier WITHOUT the vmcnt(0) drain __syncthreads carries (m97).
#define BAR() do {                                            \
    asm volatile("s_waitcnt lgkmcnt(0)" ::: "memory");        \
    __builtin_amdgcn_sched_barrier(0);                        \
    __builtin_amdgcn_s_barrier();                             \
  } while (0)

// ---------------------------------------------------------------------------
// Phase 1: per-(b,g,split) flash partials. KV caches arrive as INT32.
// R13: SWAPPED QK^T (mfma(K,Q)) + fully in-register softmax/P.
// On gfx950 the A- and B-fragment lane mappings coincide (row/col = lane&15,
// k = 8*lg+jj), so swapping operands is free. Output: col = q-row = lane&15,
// row = token = 4*lg+reg. Consequences (all subtractive vs R12):
//  - P stays in registers: the lane's 8 P values (tokens 4lg+j, 16+4lg+j of
//    q-row l15) ARE a PV A-fragment. V B-frag reads the same token map via
//    two ds_read_b64 per dt block. Plds deleted (P LDS round-trip gone).
//  - softmax: 7 in-lane fmax + 2 shfl (was 16 shfl+fmax); ell/corr are
//    per-lane partials reduced ONCE after the loop (was 8 shfl-adds/tile);
//    qsum needs no remap (already per-row-per-lane).
//  - scales: per-lane f32x4 (4 consecutive tokens), issued at tile start.
// Everything else = R12: 4 waves, fp16 pk1152 dequant, K LDS col^((row&7)<<3)
// swizzle both sides, V [d][t] transposed + token-bit XOR swizzle + 40-col
// pad, single-buffered K/V, loads for it+2 issued in locked section, raw
// s_barrier with counted vmcnt (loads stay in flight across barriers).
// ---------------------------------------------------------------------------
__global__ __launch_bounds__(256) void attn_partial(
    const float* __restrict__ q, const int* __restrict__ kc,
    const int* __restrict__ vc,
    const float* __restrict__ ksc, const float* __restrict__ kzr,
    const float* __restrict__ vsc, const float* __restrict__ vzr,
    float* __restrict__ ws_acc, float* __restrict__ ws_m,
    float* __restrict__ ws_l, int nsplit)
{
  __shared__ __align__(16) unsigned short Klds[32][128];   // fp16 bits, 8 KB
  __shared__ __align__(16) unsigned short Vlds[128][40];   // fp16 bits, 10 KB

  const int bid   = blockIdx.x;
  const int split = bid % nsplit;
  const int bg    = bid / nsplit;          // 0..31  (= b*HKV + g)
  const int chunk = KVc / nsplit;
  const int t_begin = split * chunk;
  const int nt    = chunk >> 5;            // 32-token tiles

  const int tid  = threadIdx.x;
  const int wave = tid >> 6;
  const int lane = tid & 63;
  const int l15  = lane & 15;
  const int lg   = lane >> 4;              // 0..3

  const int b = bg >> 3, g = bg & 7;
  const int h = (g << 2) + wave;           // this wave's query head

  // ---- Q fragments (fp16) + per-row sum of fp16-rounded Q ----
  f16x8 qa[4];
  float qsum = 0.f;
  const float* qrow = q + ((size_t)((b * Hc + h) * QLc + l15)) * Dc;
#pragma unroll
  for (int ks = 0; ks < 4; ++ks) {
    const f32x4* qv = (const f32x4*)(qrow + ks * 32 + (lg << 3));
    f32x4 qlo = qv[0], qhi = qv[1];
    f16x8 f;
#pragma unroll
    for (int j = 0; j < 4; ++j) {
      f[j]     = (_Float16)qlo[j];
      f[4 + j] = (_Float16)qhi[j];
      qsum += (float)f[j] + (float)f[4 + j];   // post-rounding values
    }
    qa[ks] = f;
  }
  qsum += __shfl_xor(qsum, 16);
  qsum += __shfl_xor(qsum, 32);            // every lane: qsum of row (lane&15)

  const float QK_SCALE = 0.088388347648f * 1.44269504089f; // d^-1/2 * log2(e)

  float m = -1e30f, ell = 0.f, corr = 0.f;     // per-lane: row l15 stats
  f32x4 acc[8];
#pragma unroll
  for (int dt = 0; dt < 8; ++dt) acc[dt] = (f32x4){0.f, 0.f, 0.f, 0.f};

  const int*   kb   = kc  + (size_t)bg * KVc * Dc;
  const int*   vb   = vc  + (size_t)bg * KVc * Dc;
  const float* kscb = ksc + (size_t)bg * KVc;
  const float* kzrb = kzr + (size_t)bg * KVc;
  const float* vscb = vsc + (size_t)bg * KVc;
  const float* vzrb = vzr + (size_t)bg * KVc;

  // staging coords
  const int kt  = tid >> 3;                // K: token 0..31
  const int kd  = (tid & 7) << 4;          // K: d base 0,16,...,112 (halves)
  const int ksw = (kt & 7) << 3;           // K col swizzle (u16-index XOR)
  const int tq  = tid >> 5;                // V: token group 0..7
  const int dq  = (tid & 31) << 2;         // V: d base 0,4,...,124
  const int tb  = (tq << 2) ^ ((((dq >> 4) & 3)) << 3);  // swizzled col base

  i32x4 kp[4], vp[4];                      // K/V prefetch registers (one set)

  // ---- prologue: load+write tile 0; issue tile-1 K/V ----
  {
    const int* ksrc = kb + (size_t)(t_begin + kt) * Dc + kd;
#pragma unroll
    for (int i = 0; i < 4; ++i) kp[i] = ((const i32x4*)ksrc)[i];
#pragma unroll
    for (int i = 0; i < 4; ++i)
      vp[i] = *(const i32x4*)(vb + (size_t)(t_begin + (tq << 2) + i) * Dc + dq);

    i32x4 kA, kB;
    kA[0] = (int)pk1152(kp[0][0], kp[0][1]); kA[1] = (int)pk1152(kp[0][2], kp[0][3]);
    kA[2] = (int)pk1152(kp[1][0], kp[1][1]); kA[3] = (int)pk1152(kp[1][2], kp[1][3]);
    kB[0] = (int)pk1152(kp[2][0], kp[2][1]); kB[1] = (int)pk1152(kp[2][2], kp[2][3]);
    kB[2] = (int)pk1152(kp[3][0], kp[3][1]); kB[3] = (int)pk1152(kp[3][2], kp[3][3]);
    *(i32x4*)&Klds[kt][kd ^ ksw]       = kA;
    *(i32x4*)&Klds[kt][(kd + 8) ^ ksw] = kB;
#pragma unroll
    for (int j = 0; j < 4; ++j) {
      u32x2 pk;
      pk[0] = pk1152(vp[0][j], vp[1][j]);
      pk[1] = pk1152(vp[2][j], vp[3][j]);
      *(u32x2*)&Vlds[dq + j][tb] = pk;
    }
    if (nt > 1) {                          // tile-1 loads ride across BAR
      const int* ksrc1 = kb + (size_t)(t_begin + 32 + kt) * Dc + kd;
#pragma unroll
      for (int i = 0; i < 4; ++i) kp[i] = ((const i32x4*)ksrc1)[i];
#pragma unroll
      for (int i = 0; i < 4; ++i)
        vp[i] = *(const i32x4*)(vb + (size_t)(t_begin + 32 + (tq << 2) + i) * Dc + dq);
    }
  }
  BAR();

  for (int it = 0; it < nt; ++it) {
    const int t0 = t_begin + (it << 5);

    // ---- scales: per-lane 4 consecutive tokens (16-lane-broadcast addrs) --
    const f32x4 kscp0 = *(const f32x4*)(kscb + t0 + (lg << 2));
    const f32x4 kscp1 = *(const f32x4*)(kscb + t0 + 16 + (lg << 2));
    const f32x4 kzrp0 = *(const f32x4*)(kzrb + t0 + (lg << 2));
    const f32x4 kzrp1 = *(const f32x4*)(kzrb + t0 + 16 + (lg << 2));
    const f32x4 vscp0 = *(const f32x4*)(vscb + t0 + (lg << 2));
    const f32x4 vscp1 = *(const f32x4*)(vscb + t0 + 16 + (lg << 2));
    const f32x4 vzrp0 = *(const f32x4*)(vzrb + t0 + (lg << 2));
    const f32x4 vzrp1 = *(const f32x4*)(vzrb + t0 + 16 + (lg << 2));

    // ---- QK swapped: sc = mfma(K, Q); C col = q-row l15, row = token ----
    f32x4 scA = (f32x4){0.f, 0.f, 0.f, 0.f};
    f32x4 scB = (f32x4){0.f, 0.f, 0.f, 0.f};
#pragma unroll
    for (int ks = 0; ks < 4; ++ks) {
      f16x8 kfA = *(const f16x8*)
          &Klds[l15][(ks * 32 + (lg << 3)) ^ ((l15 & 7) << 3)];
      scA = __builtin_amdgcn_mfma_f32_16x16x32_f16(kfA, qa[ks], scA, 0, 0, 0);
    }
#pragma unroll
    for (int ks = 0; ks < 4; ++ks) {
      f16x8 kfB = *(const f16x8*)
          &Klds[16 + l15][(ks * 32 + (lg << 3)) ^ ((l15 & 7) << 3)];
      scB = __builtin_amdgcn_mfma_f32_16x16x32_f16(kfB, qa[ks], scB, 0, 0, 0);
    }

    // ---- scores: s[h][j] for token t0+16h+4lg+j, q-row l15 ----
    float s0[4], s1[4];
#pragma unroll
    for (int j = 0; j < 4; ++j) {
      s0[j] = kscp0[j] * QK_SCALE * (scA[j] - (kzrp0[j] + 1152.f) * qsum);
      s1[j] = kscp1[j] * QK_SCALE * (scB[j] - (kzrp1[j] + 1152.f) * qsum);
    }

    // ---- row max: in-lane over 8, then across lg groups ----
    float tm = fmaxf(fmaxf(fmaxf(s0[0], s0[1]), fmaxf(s0[2], s0[3])),
                     fmaxf(fmaxf(s1[0], s1[1]), fmaxf(s1[2], s1[3])));
    tm = fmaxf(tm, __shfl_xor(tm, 16));
    tm = fmaxf(tm, __shfl_xor(tm, 32));
    float nm = fmaxf(m, tm);
    float cf = exp2f(m - nm);
    bool need = tm > m;
    m = nm;
    if (__any(need)) {                     // wave-uniform rescale
      ell *= cf; corr *= cf;
      float cfq[4];
#pragma unroll
      for (int j = 0; j < 4; ++j) cfq[j] = __shfl(cf, (lg << 2) + j);
#pragma unroll
      for (int dt = 0; dt < 8; ++dt)
#pragma unroll
        for (int j = 0; j < 4; ++j) acc[dt][j] *= cfq[j];
    }

    // ---- P in registers: P'' = p*vs*1024 fp16; corr uses ROUNDED P'' ----
    f16x8 pp;
#pragma unroll
    for (int j = 0; j < 4; ++j) {
      float pA = exp2f(s0[j] - m);
      float pB = exp2f(s1[j] - m);
      ell += pA + pB;
      _Float16 ca = (_Float16)(pA * (vscp0[j] * 1024.f));
      _Float16 cb = (_Float16)(pB * (vscp1[j] * 1024.f));
      corr += (float)ca * (vzrp0[j] + 1152.f) + (float)cb * (vzrp1[j] + 1152.f);
      pp[j]     = ca;                      // k-slot j   -> token 4lg+j
      pp[4 + j] = cb;                      // k-slot 4+j -> token 16+4lg+j
    }

    // ---- PV: acc = mfma(P, V); V B-frag = same token map (2x b64 / dt) ----
#pragma unroll
    for (int dt = 0; dt < 8; ++dt) {
      const int swz = (dt & 3) << 3;
      f16x4 vA = *(const f16x4*)&Vlds[(dt << 4) + l15][(lg << 2) ^ swz];
      f16x4 vB = *(const f16x4*)&Vlds[(dt << 4) + l15][(16 + (lg << 2)) ^ swz];
      f16x8 vf = __builtin_shufflevector(vA, vB, 0, 1, 2, 3, 4, 5, 6, 7);
      acc[dt] = __builtin_amdgcn_mfma_f32_16x16x32_f16(pp, vf, acc[dt], 0, 0, 0);
    }

    // ---- locked section: write it+1; issue it+2 K/V ----
    if (it + 1 < nt) {
      BAR();                               // reads done (no vmcnt drain)
      i32x4 kA, kB;                        // counted vmcnt wait for kp/vp here
      kA[0] = (int)pk1152(kp[0][0], kp[0][1]); kA[1] = (int)pk1152(kp[0][2], kp[0][3]);
      kA[2] = (int)pk1152(kp[1][0], kp[1][1]); kA[3] = (int)pk1152(kp[1][2], kp[1][3]);
      kB[0] = (int)pk1152(kp[2][0], kp[2][1]); kB[1] = (int)pk1152(kp[2][2], kp[2][3]);
      kB[2] = (int)pk1152(kp[3][0], kp[3][1]); kB[3] = (int)pk1152(kp[3][2], kp[3][3]);
      *(i32x4*)&Klds[kt][kd ^ ksw]       = kA;
      *(i32x4*)&Klds[kt][(kd + 8) ^ ksw] = kB;
#pragma unroll
      for (int j = 0; j < 4; ++j) {
        u32x2 pk;
        pk[0] = pk1152(vp[0][j], vp[1][j]);
        pk[1] = pk1152(vp[2][j], vp[3][j]);
        *(u32x2*)&Vlds[dq + j][tb] = pk;
      }
      if (it + 2 < nt) {                   // in flight across BAR + compute
        const int tn2 = t0 + 64;
        const int* ksrc = kb + (size_t)(tn2 + kt) * Dc + kd;
#pragma unroll
        for (int i = 0; i < 4; ++i) kp[i] = ((const i32x4*)ksrc)[i];
#pragma unroll
        for (int i = 0; i < 4; ++i)
          vp[i] = *(const i32x4*)(vb + (size_t)(tn2 + (tq << 2) + i) * Dc + dq);
      }
      BAR();                               // writes visible (lgkmcnt only)
    }
  }

  // ---- final reductions: ell/corr across lg groups (row l15) ----
  ell += __shfl_xor(ell, 16);  ell += __shfl_xor(ell, 32);
  corr += __shfl_xor(corr, 16); corr += __shfl_xor(corr, 32);
  float corrq[4];
#pragma unroll
  for (int j = 0; j < 4; ++j) corrq[j] = __shfl(corr, (lg << 2) + j);

  const size_t pbase = ((size_t)bg * nsplit + split) * 64;
  const float inv1k = 0.0009765625f;       // 1/1024 (undo P'' scaling)
#pragma unroll
  for (int dt = 0; dt < 8; ++dt)
#pragma unroll
    for (int j = 0; j < 4; ++j) {
      int row = (wave << 4) + (lg << 2) + j;   // q-row
      int d   = (dt << 4) + l15;
      ws_acc[(pbase + row) * Dc + d] = (acc[dt][j] - corrq[j]) * inv1k;
    }
  if (lg == 0) {
    ws_m[pbase + (wave << 4) + l15] = m;
    ws_l[pbase + (wave << 4) + l15] = ell;
  }
}

// ---------------------------------------------------------------------------
// Phase 2: flash-combine partials and normalize. One block per (bg,row).
// ---------------------------------------------------------------------------
__global__ __launch_bounds__(128) void attn_combine(
    const float* __restrict__ ws_acc, const float* __restrict__ ws_m,
    const float* __restrict__ ws_l, float* __restrict__ out, int nsplit)
{
  const int r   = blockIdx.x;      // 0 .. 32*64-1
  const int bg  = r >> 6;
  const int row = r & 63;
  const int d   = threadIdx.x;     // 0..127

  float M = -1e30f;
#pragma unroll 4
  for (int i = 0; i < nsplit; ++i)
    M = fmaxf(M, ws_m[((size_t)bg * nsplit + i) * 64 + row]);
  float L = 0.f, o = 0.f;
#pragma unroll 4
  for (int i = 0; i < nsplit; ++i) {
    size_t pb = ((size_t)bg * nsplit + i) * 64 + row;
    float w = exp2f(ws_m[pb] - M);
    L += ws_l[pb] * w;
    o += ws_acc[pb * Dc + d] * w;
  }
  const int b = bg >> 3, g = bg & 7;
  const int rep = row >> 4, qq = row & 15;
  out[(((size_t)(b * Hc + g * NREPc + rep)) * QLc + qq) * Dc + d] = o / L;
}

extern "C" void kernel_launch(void* const* d_in, const int* in_sizes, int n_in,
                              void* d_out, int out_size, void* d_ws,
                              size_t ws_size, hipStream_t stream) {
  const float* q   = (const float*)d_in[0];
  const int*   kc  = (const int*)d_in[1];   // int8 values promoted to int32
  const int*   vc  = (const int*)d_in[2];
  const float* ksc = (const float*)d_in[3];
  const float* kzr = (const float*)d_in[4];
  const float* vsc = (const float*)d_in[5];
  const float* vzr = (const float*)d_in[6];
  float* out = (float*)d_out;

  int nsplit = 64;                         // 2048 blocks; fallback if ws small
  while (nsplit > 1) {
    size_t need = (size_t)32 * nsplit * 64 * (Dc + 2) * sizeof(float);
    if (need <= ws_size) break;
    nsplit >>= 1;
  }
  float* ws_acc = (float*)d_ws;                             // [32,ns,64,128]
  float* ws_m   = ws_acc + (size_t)32 * nsplit * 64 * Dc;   // [32,ns,64]
  float* ws_l   = ws_m   + (size_t)32 * nsplit * 64;        // [32,ns,64]

  attn_partial<<<dim3(32 * nsplit), dim3(256), 0, stream>>>(
      q, kc, vc, ksc, kzr, vsc, vzr, ws_acc, ws_m, ws_l, nsplit);
  attn_combine<<<dim3(32 * 64), dim3(128), 0, stream>>>(
      ws_acc, ws_m, ws_l, out, nsplit);
}

// Round 15
// 100.077 us; speedup vs baseline: 1.0862x; 1.0862x over previous
//
#include <hip/hip_runtime.h>
#include <hip/hip_bf16.h>
#include <stdint.h>

// Problem constants (CompressedKVAttention_11708080848911)
#define Bc    4
#define Hc    32
#define HKVc  8
#define QLc   16
#define KVc   8192
#define Dc    128
#define NREPc 4   // H / HKV
#define THR   8.0f   // defer-max threshold (T13); P <= 2^8, P''<=5243 < fp16 max

typedef _Float16 f16x8 __attribute__((ext_vector_type(8)));
typedef _Float16 f16x4 __attribute__((ext_vector_type(4)));
typedef float f32x4  __attribute__((ext_vector_type(4)));
typedef int   i32x4  __attribute__((ext_vector_type(4)));
typedef uint32_t u32x2 __attribute__((ext_vector_type(2)));

// Pack two sign-extended-int8 dwords into one half2 = (x0+1152, x1+1152).
// fp16 0x6400|u = 1024+u (u in [0,255] exact); u = byte^0x80 = x+128.
__device__ __forceinline__ uint32_t pk1152(int x0, int x1) {
  return (__builtin_amdgcn_perm((uint32_t)x1, (uint32_t)x0, 0x05040100u)
          & 0x00FF00FFu) ^ 0x64806480u;
}

// Raw barrier WITHOUT the vmcnt(0) drain __syncthreads carries (m97).
#define BAR() do {                                            \
    asm volatile("s_waitcnt lgkmcnt(0)" ::: "memory");        \
    __builtin_amdgcn_sched_barrier(0);                        \
    __builtin_amdgcn_s_barrier();                             \
  } while (0)

// ---------------------------------------------------------------------------
// R14: attack the per-tile serial chain (R6-R13 invariant ~112us = ~2.1K
// cy/tile x 16 tiles x ~5 sequential block-rounds/CU; R4 showed residency is
// NOT the binding constraint):
//  1) Scales PREFOLDED into LDS once per 256-token window (ksc*scale,
//     kz+1152, vs*1024, vz+1152): per-tile scale access = broadcast
//     ds_read_b128, zero VMEM latency on the chain (R13 re-exposed ~1-2Kcy
//     of scale-load latency every tile).
//  2) 2-deep K/V prefetch via two NAMED reg sets (rule #20): loads for tile
//     t+3 issued in locked(t) -> in flight across TWO compute phases.
//  3) T13 defer-max THR=8: the rescale path (2+4 bpermute-class shuffles +
//     32-mul acc scale) fires only when tm > m+8 (early tiles).
//  4) QK accumulator split (ks01/ks23 chains, added at end).
// Base = R13: swapped QK^T (mfma(K,Q)), P fully in registers, fp16 pk1152
// dequant, K swizzle col^((row&7)<<3) both sides, V [d][t]+XOR+40-pad,
// single-buffered K/V, raw s_barrier (loads ride across barriers).
// ---------------------------------------------------------------------------
__global__ __launch_bounds__(256) void attn_partial(
    const float* __restrict__ q, const int* __restrict__ kc,
    const int* __restrict__ vc,
    const float* __restrict__ ksc, const float* __restrict__ kzr,
    const float* __restrict__ vsc, const float* __restrict__ vzr,
    float* __restrict__ ws_acc, float* __restrict__ ws_m,
    float* __restrict__ ws_l, int nsplit)
{
  __shared__ __align__(16) unsigned short Klds[32][128];   // fp16 bits, 8 KB
  __shared__ __align__(16) unsigned short Vlds[128][40];   // fp16 bits, 10 KB
  __shared__ __align__(16) float          Sl[4][256];      // scales, 4 KB

  const int bid   = blockIdx.x;
  const int split = bid % nsplit;
  const int bg    = bid / nsplit;          // 0..31  (= b*HKV + g)
  const int chunk = KVc / nsplit;
  const int t_begin = split * chunk;
  const int nt    = chunk >> 5;            // 32-token tiles

  const int tid  = threadIdx.x;
  const int wave = tid >> 6;
  const int lane = tid & 63;
  const int l15  = lane & 15;
  const int lg   = lane >> 4;              // 0..3

  const int b = bg >> 3, g = bg & 7;
  const int h = (g << 2) + wave;           // this wave's query head

  // ---- Q fragments (fp16) + per-row sum of fp16-rounded Q ----
  f16x8 qa[4];
  float qsum = 0.f;
  const float* qrow = q + ((size_t)((b * Hc + h) * QLc + l15)) * Dc;
#pragma unroll
  for (int ks = 0; ks < 4; ++ks) {
    const f32x4* qv = (const f32x4*)(qrow + ks * 32 + (lg << 3));
    f32x4 qlo = qv[0], qhi = qv[1];
    f16x8 f;
#pragma unroll
    for (int j = 0; j < 4; ++j) {
      f[j]     = (_Float16)qlo[j];
      f[4 + j] = (_Float16)qhi[j];
      qsum += (float)f[j] + (float)f[4 + j];   // post-rounding values
    }
    qa[ks] = f;
  }
  qsum += __shfl_xor(qsum, 16);
  qsum += __shfl_xor(qsum, 32);            // every lane: qsum of row (lane&15)

  const float QK_SCALE = 0.088388347648f * 1.44269504089f; // d^-1/2 * log2(e)

  float m = -1e30f, ell = 0.f, corr = 0.f;     // per-lane: row l15 stats
  f32x4 acc[8];
#pragma unroll
  for (int dt = 0; dt < 8; ++dt) acc[dt] = (f32x4){0.f, 0.f, 0.f, 0.f};

  const int*   kb   = kc  + (size_t)bg * KVc * Dc;
  const int*   vb   = vc  + (size_t)bg * KVc * Dc;
  const float* kscb = ksc + (size_t)bg * KVc;
  const float* kzrb = kzr + (size_t)bg * KVc;
  const float* vscb = vsc + (size_t)bg * KVc;
  const float* vzrb = vzr + (size_t)bg * KVc;

  // staging coords
  const int kt  = tid >> 3;                // K: token 0..31
  const int kd  = (tid & 7) << 4;          // K: d base (dwords in / halves out)
  const int ksw = (kt & 7) << 3;           // K col swizzle (u16-index XOR)
  const int tq  = tid >> 5;                // V: token group 0..7
  const int dq  = (tid & 31) << 2;         // V: d base 0,4,...,124
  const int tb  = (tq << 2) ^ ((((dq >> 4) & 3)) << 3);  // swizzled col base

  i32x4 kpA[4], vpA[4], kpB[4], vpB[4];    // two named prefetch sets

#define ISSUE(KP, VP, TILE) do {                                             \
    const int _t0 = t_begin + ((TILE) << 5);                                 \
    const int* _ks = kb + (size_t)(_t0 + kt) * Dc + kd;                      \
    KP[0] = ((const i32x4*)_ks)[0]; KP[1] = ((const i32x4*)_ks)[1];          \
    KP[2] = ((const i32x4*)_ks)[2]; KP[3] = ((const i32x4*)_ks)[3];          \
    VP[0] = *(const i32x4*)(vb + (size_t)(_t0 + (tq << 2) + 0) * Dc + dq);   \
    VP[1] = *(const i32x4*)(vb + (size_t)(_t0 + (tq << 2) + 1) * Dc + dq);   \
    VP[2] = *(const i32x4*)(vb + (size_t)(_t0 + (tq << 2) + 2) * Dc + dq);   \
    VP[3] = *(const i32x4*)(vb + (size_t)(_t0 + (tq << 2) + 3) * Dc + dq);   \
  } while (0)

#define WRITE(KP, VP) do {                                                   \
    i32x4 _kA, _kB;                                                          \
    _kA[0]=(int)pk1152(KP[0][0],KP[0][1]); _kA[1]=(int)pk1152(KP[0][2],KP[0][3]); \
    _kA[2]=(int)pk1152(KP[1][0],KP[1][1]); _kA[3]=(int)pk1152(KP[1][2],KP[1][3]); \
    _kB[0]=(int)pk1152(KP[2][0],KP[2][1]); _kB[1]=(int)pk1152(KP[2][2],KP[2][3]); \
    _kB[2]=(int)pk1152(KP[3][0],KP[3][1]); _kB[3]=(int)pk1152(KP[3][2],KP[3][3]); \
    *(i32x4*)&Klds[kt][kd ^ ksw]       = _kA;                                \
    *(i32x4*)&Klds[kt][(kd + 8) ^ ksw] = _kB;                                \
    _Pragma("unroll")                                                        \
    for (int _j = 0; _j < 4; ++_j) {                                         \
      u32x2 _pk;                                                             \
      _pk[0] = pk1152(VP[0][_j], VP[1][_j]);                                 \
      _pk[1] = pk1152(VP[2][_j], VP[3][_j]);                                 \
      *(u32x2*)&Vlds[dq + _j][tb] = _pk;                                     \
    }                                                                        \
  } while (0)

  // Prefolded scale restage for a 256-token window starting at WBASE.
#define RESTAGE(WBASE) do {                                                  \
    const int _arr = tid >> 6;                                               \
    const int _sl  = (tid & 63) << 2;                                        \
    int _toff = _sl;                                                         \
    if (_toff > chunk - 4) _toff = chunk - 4;                                \
    const float* _sp = (_arr == 0) ? kscb : (_arr == 1) ? kzrb               \
                     : (_arr == 2) ? vscb : vzrb;                            \
    f32x4 _sv = *(const f32x4*)(_sp + (WBASE) + _toff);                      \
    if (_arr == 0) { _sv[0]*=QK_SCALE; _sv[1]*=QK_SCALE;                     \
                     _sv[2]*=QK_SCALE; _sv[3]*=QK_SCALE; }                   \
    else if (_arr == 2) { _sv[0]*=1024.f; _sv[1]*=1024.f;                    \
                          _sv[2]*=1024.f; _sv[3]*=1024.f; }                  \
    else { _sv[0]+=1152.f; _sv[1]+=1152.f; _sv[2]+=1152.f; _sv[3]+=1152.f; } \
    *(f32x4*)&Sl[_arr][_sl] = _sv;                                           \
  } while (0)

  // ---- prologue: tile0 staged; tile1->A, tile2->B in flight; scales ----
  ISSUE(kpA, vpA, 0);
  RESTAGE(t_begin);                        // overlaps tile0 load latency
  WRITE(kpA, vpA);                         // waits tile0 loads
  if (nt > 1) ISSUE(kpA, vpA, 1);
  if (nt > 2) ISSUE(kpB, vpB, 2);
  BAR();

  for (int it = 0; it < nt; ++it) {
    if (it && !(it & 7)) {                 // new 256-token scale window
      RESTAGE(t_begin + ((it >> 3) << 8));
      BAR();
    }

    // ---- scales from LDS (prefolded; broadcast reads, off VMEM path) ----
    const int tw = (it & 7) << 5;
    const f32x4 ksc0 = *(const f32x4*)&Sl[0][tw + (lg << 2)];
    const f32x4 ksc1 = *(const f32x4*)&Sl[0][tw + 16 + (lg << 2)];
    const f32x4 kzr0 = *(const f32x4*)&Sl[1][tw + (lg << 2)];
    const f32x4 kzr1 = *(const f32x4*)&Sl[1][tw + 16 + (lg << 2)];
    const f32x4 vsc0 = *(const f32x4*)&Sl[2][tw + (lg << 2)];
    const f32x4 vsc1 = *(const f32x4*)&Sl[2][tw + 16 + (lg << 2)];
    const f32x4 vzr0 = *(const f32x4*)&Sl[3][tw + (lg << 2)];
    const f32x4 vzr1 = *(const f32x4*)&Sl[3][tw + 16 + (lg << 2)];

    // ---- QK swapped, split accumulator chains ----
    f32x4 sA0 = (f32x4){0.f,0.f,0.f,0.f}, sA1 = (f32x4){0.f,0.f,0.f,0.f};
    f32x4 sB0 = (f32x4){0.f,0.f,0.f,0.f}, sB1 = (f32x4){0.f,0.f,0.f,0.f};
#pragma unroll
    for (int ks = 0; ks < 2; ++ks) {
      f16x8 kfA = *(const f16x8*)
          &Klds[l15][(ks * 32 + (lg << 3)) ^ ((l15 & 7) << 3)];
      sA0 = __builtin_amdgcn_mfma_f32_16x16x32_f16(kfA, qa[ks], sA0, 0, 0, 0);
      f16x8 kfB = *(const f16x8*)
          &Klds[16 + l15][(ks * 32 + (lg << 3)) ^ ((l15 & 7) << 3)];
      sB0 = __builtin_amdgcn_mfma_f32_16x16x32_f16(kfB, qa[ks], sB0, 0, 0, 0);
    }
#pragma unroll
    for (int ks = 2; ks < 4; ++ks) {
      f16x8 kfA = *(const f16x8*)
          &Klds[l15][(ks * 32 + (lg << 3)) ^ ((l15 & 7) << 3)];
      sA1 = __builtin_amdgcn_mfma_f32_16x16x32_f16(kfA, qa[ks], sA1, 0, 0, 0);
      f16x8 kfB = *(const f16x8*)
          &Klds[16 + l15][(ks * 32 + (lg << 3)) ^ ((l15 & 7) << 3)];
      sB1 = __builtin_amdgcn_mfma_f32_16x16x32_f16(kfB, qa[ks], sB1, 0, 0, 0);
    }
    const f32x4 scA = sA0 + sA1;
    const f32x4 scB = sB0 + sB1;

    // ---- scores (scales prefolded) ----
    float s0[4], s1[4];
#pragma unroll
    for (int j = 0; j < 4; ++j) {
      s0[j] = ksc0[j] * (scA[j] - kzr0[j] * qsum);
      s1[j] = ksc1[j] * (scB[j] - kzr1[j] * qsum);
    }

    // ---- T13 defer-max: rescale only when tile max exceeds m+THR ----
    float tm = fmaxf(fmaxf(fmaxf(s0[0], s0[1]), fmaxf(s0[2], s0[3])),
                     fmaxf(fmaxf(s1[0], s1[1]), fmaxf(s1[2], s1[3])));
    tm = fmaxf(tm, __shfl_xor(tm, 16));
    tm = fmaxf(tm, __shfl_xor(tm, 32));
    if (__any(tm > m + THR)) {             // rare after early tiles
      float nm = fmaxf(m, tm);
      float cf = exp2f(m - nm);
      m = nm;
      ell *= cf; corr *= cf;
      float cfq[4];
#pragma unroll
      for (int j = 0; j < 4; ++j) cfq[j] = __shfl(cf, (lg << 2) + j);
#pragma unroll
      for (int dt = 0; dt < 8; ++dt)
#pragma unroll
        for (int j = 0; j < 4; ++j) acc[dt][j] *= cfq[j];
    }

    // ---- P in registers (P'' = p*vs*1024, prefolded); corr on ROUNDED P'' --
    f16x8 pp;
#pragma unroll
    for (int j = 0; j < 4; ++j) {
      float pA = exp2f(s0[j] - m);
      float pB = exp2f(s1[j] - m);
      ell += pA + pB;
      _Float16 ca = (_Float16)(pA * vsc0[j]);
      _Float16 cb = (_Float16)(pB * vsc1[j]);
      corr += (float)ca * vzr0[j] + (float)cb * vzr1[j];
      pp[j]     = ca;                      // k-slot j   -> token 4lg+j
      pp[4 + j] = cb;                      // k-slot 4+j -> token 16+4lg+j
    }

    // ---- PV: acc = mfma(P, V) ----
#pragma unroll
    for (int dt = 0; dt < 8; ++dt) {
      const int swz = (dt & 3) << 3;
      f16x4 vA = *(const f16x4*)&Vlds[(dt << 4) + l15][(lg << 2) ^ swz];
      f16x4 vB = *(const f16x4*)&Vlds[(dt << 4) + l15][(16 + (lg << 2)) ^ swz];
      f16x8 vf = __builtin_shufflevector(vA, vB, 0, 1, 2, 3, 4, 5, 6, 7);
      acc[dt] = __builtin_amdgcn_mfma_f32_16x16x32_f16(pp, vf, acc[dt], 0, 0, 0);
    }

    // ---- locked: write tile it+1 (2 computes in flight); reissue its set --
    if (it + 1 < nt) {
      if (it & 1) {
        BAR();
        WRITE(kpB, vpB);
        if (it + 3 < nt) ISSUE(kpB, vpB, it + 3);
        BAR();
      } else {
        BAR();
        WRITE(kpA, vpA);
        if (it + 3 < nt) ISSUE(kpA, vpA, it + 3);
        BAR();
      }
    }
  }

  // ---- final reductions: ell/corr across lg groups (row l15) ----
  ell += __shfl_xor(ell, 16);  ell += __shfl_xor(ell, 32);
  corr += __shfl_xor(corr, 16); corr += __shfl_xor(corr, 32);
  float corrq[4];
#pragma unroll
  for (int j = 0; j < 4; ++j) corrq[j] = __shfl(corr, (lg << 2) + j);

  const size_t pbase = ((size_t)bg * nsplit + split) * 64;
  const float inv1k = 0.0009765625f;       // 1/1024 (undo P'' scaling)
#pragma unroll
  for (int dt = 0; dt < 8; ++dt)
#pragma unroll
    for (int j = 0; j < 4; ++j) {
      int row = (wave << 4) + (lg << 2) + j;   // q-row
      int d   = (dt << 4) + l15;
      ws_acc[(pbase + row) * Dc + d] = (acc[dt][j] - corrq[j]) * inv1k;
    }
  if (lg == 0) {
    ws_m[pbase + (wave << 4) + l15] = m;
    ws_l[pbase + (wave << 4) + l15] = ell;
  }
#undef ISSUE
#undef WRITE
#undef RESTAGE
}

// ---------------------------------------------------------------------------
// Phase 2: flash-combine partials and normalize. One block per (bg,row).
// ---------------------------------------------------------------------------
__global__ __launch_bounds__(128) void attn_combine(
    const float* __restrict__ ws_acc, const float* __restrict__ ws_m,
    const float* __restrict__ ws_l, float* __restrict__ out, int nsplit)
{
  const int r   = blockIdx.x;      // 0 .. 32*64-1
  const int bg  = r >> 6;
  const int row = r & 63;
  const int d   = threadIdx.x;     // 0..127

  float M = -1e30f;
#pragma unroll 4
  for (int i = 0; i < nsplit; ++i)
    M = fmaxf(M, ws_m[((size_t)bg * nsplit + i) * 64 + row]);
  float L = 0.f, o = 0.f;
#pragma unroll 4
  for (int i = 0; i < nsplit; ++i) {
    size_t pb = ((size_t)bg * nsplit + i) * 64 + row;
    float w = exp2f(ws_m[pb] - M);
    L += ws_l[pb] * w;
    o += ws_acc[pb * Dc + d] * w;
  }
  const int b = bg >> 3, g = bg & 7;
  const int rep = row >> 4, qq = row & 15;
  out[(((size_t)(b * Hc + g * NREPc + rep)) * QLc + qq) * Dc + d] = o / L;
}

extern "C" void kernel_launch(void* const* d_in, const int* in_sizes, int n_in,
                              void* d_out, int out_size, void* d_ws,
                              size_t ws_size, hipStream_t stream) {
  const float* q   = (const float*)d_in[0];
  const int*   kc  = (const int*)d_in[1];   // int8 values promoted to int32
  const int*   vc  = (const int*)d_in[2];
  const float* ksc = (const float*)d_in[3];
  const float* kzr = (const float*)d_in[4];
  const float* vsc = (const float*)d_in[5];
  const float* vzr = (const float*)d_in[6];
  float* out = (float*)d_out;

  int nsplit = 64;                         // 2048 blocks; fallback if ws small
  while (nsplit > 1) {
    size_t need = (size_t)32 * nsplit * 64 * (Dc + 2) * sizeof(float);
    if (need <= ws_size) break;
    nsplit >>= 1;
  }
  float* ws_acc = (float*)d_ws;                             // [32,ns,64,128]
  float* ws_m   = ws_acc + (size_t)32 * nsplit * 64 * Dc;   // [32,ns,64]
  float* ws_l   = ws_m   + (size_t)32 * nsplit * 64;        // [32,ns,64]

  attn_partial<<<dim3(32 * nsplit), dim3(256), 0, stream>>>(
      q, kc, vc, ksc, kzr, vsc, vzr, ws_acc, ws_m, ws_l, nsplit);
  attn_combine<<<dim3(32 * 64), dim3(128), 0, stream>>>(
      ws_acc, ws_m, ws_l, out, nsplit);
}

// Round 16
// 79.108 us; speedup vs baseline: 1.3741x; 1.2651x over previous
//
#include <hip/hip_runtime.h>
#include <hip/hip_bf16.h>
#include <stdint.h>

// Problem constants (CompressedKVAttention_11708080848911)
#define Bc    4
#define Hc    32
#define HKVc  8
#define QLc   16
#define KVc   8192
#define Dc    128
#define NREPc 4   // H / HKV
#define THR   8.0f   // defer-max threshold (T13); P <= 2^8, P''<=5243 < fp16 max

typedef _Float16 f16x8 __attribute__((ext_vector_type(8)));
typedef _Float16 f16x4 __attribute__((ext_vector_type(4)));
typedef float f32x4  __attribute__((ext_vector_type(4)));
typedef int   i32x4  __attribute__((ext_vector_type(4)));
typedef uint32_t u32x2 __attribute__((ext_vector_type(2)));

// Pack two sign-extended-int8 dwords into one half2 = (x0+1152, x1+1152).
// fp16 0x6400|u = 1024+u (u in [0,255] exact); u = byte^0x80 = x+128.
__device__ __forceinline__ uint32_t pk1152(int x0, int x1) {
  return (__builtin_amdgcn_perm((uint32_t)x1, (uint32_t)x0, 0x05040100u)
          & 0x00FF00FFu) ^ 0x64806480u;
}

// Raw barrier WITHOUT the vmcnt(0) drain __syncthreads carries (m97).
#define BAR() do {                                            \
    asm volatile("s_waitcnt lgkmcnt(0)" ::: "memory");        \
    __builtin_amdgcn_sched_barrier(0);                        \
    __builtin_amdgcn_s_barrier();                             \
  } while (0)

// ---------------------------------------------------------------------------
// R15 (R14 = 100us, first win since R9; combine ~10-12us = pure ws tax;
// nt=4 made the block prologue 30-40% of block time; 8 blocks/CU needed
// ~2+ sequential rounds at the 4-block VGPR residency cap):
//  1) nsplit 64->32: grid 1024 = 4 blocks/CU = exactly the residency cap ->
//     ALL blocks co-resident, no sequential rounds; nt=8 halves prologue
//     amortized cost; ws traffic halves (67->34 MB each way).
//  2) T5 s_setprio(1) around QK and PV MFMA clusters (phase-split structure
//     is the regime where setprio pays: m191/m218b).
//  3) Scales: one RESTAGE in prologue (Sl = 256 tokens = whole chunk now).
// Base = R14: swapped QK^T, in-register P, prefolded LDS scales, 2-deep
// named prefetch, T13 defer-max, fp16 pk1152 dequant, K swizzle both sides,
// V [d][t]+XOR+40-pad, raw s_barrier (loads ride across barriers).
// ---------------------------------------------------------------------------
__global__ __launch_bounds__(256) void attn_partial(
    const float* __restrict__ q, const int* __restrict__ kc,
    const int* __restrict__ vc,
    const float* __restrict__ ksc, const float* __restrict__ kzr,
    const float* __restrict__ vsc, const float* __restrict__ vzr,
    float* __restrict__ ws_acc, float* __restrict__ ws_m,
    float* __restrict__ ws_l, int nsplit)
{
  __shared__ __align__(16) unsigned short Klds[32][128];   // fp16 bits, 8 KB
  __shared__ __align__(16) unsigned short Vlds[128][40];   // fp16 bits, 10 KB
  __shared__ __align__(16) float          Sl[4][256];      // scales, 4 KB

  const int bid   = blockIdx.x;
  const int split = bid % nsplit;
  const int bg    = bid / nsplit;          // 0..31  (= b*HKV + g)
  const int chunk = KVc / nsplit;
  const int t_begin = split * chunk;
  const int nt    = chunk >> 5;            // 32-token tiles

  const int tid  = threadIdx.x;
  const int wave = tid >> 6;
  const int lane = tid & 63;
  const int l15  = lane & 15;
  const int lg   = lane >> 4;              // 0..3

  const int b = bg >> 3, g = bg & 7;
  const int h = (g << 2) + wave;           // this wave's query head

  // ---- Q fragments (fp16) + per-row sum of fp16-rounded Q ----
  f16x8 qa[4];
  float qsum = 0.f;
  const float* qrow = q + ((size_t)((b * Hc + h) * QLc + l15)) * Dc;
#pragma unroll
  for (int ks = 0; ks < 4; ++ks) {
    const f32x4* qv = (const f32x4*)(qrow + ks * 32 + (lg << 3));
    f32x4 qlo = qv[0], qhi = qv[1];
    f16x8 f;
#pragma unroll
    for (int j = 0; j < 4; ++j) {
      f[j]     = (_Float16)qlo[j];
      f[4 + j] = (_Float16)qhi[j];
      qsum += (float)f[j] + (float)f[4 + j];   // post-rounding values
    }
    qa[ks] = f;
  }
  qsum += __shfl_xor(qsum, 16);
  qsum += __shfl_xor(qsum, 32);            // every lane: qsum of row (lane&15)

  const float QK_SCALE = 0.088388347648f * 1.44269504089f; // d^-1/2 * log2(e)

  float m = -1e30f, ell = 0.f, corr = 0.f;     // per-lane: row l15 stats
  f32x4 acc[8];
#pragma unroll
  for (int dt = 0; dt < 8; ++dt) acc[dt] = (f32x4){0.f, 0.f, 0.f, 0.f};

  const int*   kb   = kc  + (size_t)bg * KVc * Dc;
  const int*   vb   = vc  + (size_t)bg * KVc * Dc;
  const float* kscb = ksc + (size_t)bg * KVc;
  const float* kzrb = kzr + (size_t)bg * KVc;
  const float* vscb = vsc + (size_t)bg * KVc;
  const float* vzrb = vzr + (size_t)bg * KVc;

  // staging coords
  const int kt  = tid >> 3;                // K: token 0..31
  const int kd  = (tid & 7) << 4;          // K: d base (dwords in / halves out)
  const int ksw = (kt & 7) << 3;           // K col swizzle (u16-index XOR)
  const int tq  = tid >> 5;                // V: token group 0..7
  const int dq  = (tid & 31) << 2;         // V: d base 0,4,...,124
  const int tb  = (tq << 2) ^ ((((dq >> 4) & 3)) << 3);  // swizzled col base

  i32x4 kpA[4], vpA[4], kpB[4], vpB[4];    // two named prefetch sets

#define ISSUE(KP, VP, TILE) do {                                             \
    const int _t0 = t_begin + ((TILE) << 5);                                 \
    const int* _ks = kb + (size_t)(_t0 + kt) * Dc + kd;                      \
    KP[0] = ((const i32x4*)_ks)[0]; KP[1] = ((const i32x4*)_ks)[1];          \
    KP[2] = ((const i32x4*)_ks)[2]; KP[3] = ((const i32x4*)_ks)[3];          \
    VP[0] = *(const i32x4*)(vb + (size_t)(_t0 + (tq << 2) + 0) * Dc + dq);   \
    VP[1] = *(const i32x4*)(vb + (size_t)(_t0 + (tq << 2) + 1) * Dc + dq);   \
    VP[2] = *(const i32x4*)(vb + (size_t)(_t0 + (tq << 2) + 2) * Dc + dq);   \
    VP[3] = *(const i32x4*)(vb + (size_t)(_t0 + (tq << 2) + 3) * Dc + dq);   \
  } while (0)

#define WRITE(KP, VP) do {                                                   \
    i32x4 _kA, _kB;                                                          \
    _kA[0]=(int)pk1152(KP[0][0],KP[0][1]); _kA[1]=(int)pk1152(KP[0][2],KP[0][3]); \
    _kA[2]=(int)pk1152(KP[1][0],KP[1][1]); _kA[3]=(int)pk1152(KP[1][2],KP[1][3]); \
    _kB[0]=(int)pk1152(KP[2][0],KP[2][1]); _kB[1]=(int)pk1152(KP[2][2],KP[2][3]); \
    _kB[2]=(int)pk1152(KP[3][0],KP[3][1]); _kB[3]=(int)pk1152(KP[3][2],KP[3][3]); \
    *(i32x4*)&Klds[kt][kd ^ ksw]       = _kA;                                \
    *(i32x4*)&Klds[kt][(kd + 8) ^ ksw] = _kB;                                \
    _Pragma("unroll")                                                        \
    for (int _j = 0; _j < 4; ++_j) {                                         \
      u32x2 _pk;                                                             \
      _pk[0] = pk1152(VP[0][_j], VP[1][_j]);                                 \
      _pk[1] = pk1152(VP[2][_j], VP[3][_j]);                                 \
      *(u32x2*)&Vlds[dq + _j][tb] = _pk;                                     \
    }                                                                        \
  } while (0)

  // Prefolded scale restage for a 256-token window starting at WBASE.
#define RESTAGE(WBASE) do {                                                  \
    const int _arr = tid >> 6;                                               \
    const int _sl  = (tid & 63) << 2;                                        \
    int _toff = _sl;                                                         \
    if (_toff > chunk - 4) _toff = chunk - 4;                                \
    const float* _sp = (_arr == 0) ? kscb : (_arr == 1) ? kzrb               \
                     : (_arr == 2) ? vscb : vzrb;                            \
    f32x4 _sv = *(const f32x4*)(_sp + (WBASE) + _toff);                      \
    if (_arr == 0) { _sv[0]*=QK_SCALE; _sv[1]*=QK_SCALE;                     \
                     _sv[2]*=QK_SCALE; _sv[3]*=QK_SCALE; }                   \
    else if (_arr == 2) { _sv[0]*=1024.f; _sv[1]*=1024.f;                    \
                          _sv[2]*=1024.f; _sv[3]*=1024.f; }                  \
    else { _sv[0]+=1152.f; _sv[1]+=1152.f; _sv[2]+=1152.f; _sv[3]+=1152.f; } \
    *(f32x4*)&Sl[_arr][_sl] = _sv;                                           \
  } while (0)

  // ---- prologue: tile0 staged; tile1->A, tile2->B in flight; scales ----
  ISSUE(kpA, vpA, 0);
  RESTAGE(t_begin);                        // overlaps tile0 load latency
  WRITE(kpA, vpA);                         // waits tile0 loads
  if (nt > 1) ISSUE(kpA, vpA, 1);
  if (nt > 2) ISSUE(kpB, vpB, 2);
  BAR();

  for (int it = 0; it < nt; ++it) {
    if (it && !(it & 7)) {                 // new 256-token scale window
      RESTAGE(t_begin + ((it >> 3) << 8));
      BAR();
    }

    // ---- scales from LDS (prefolded; broadcast reads, off VMEM path) ----
    const int tw = (it & 7) << 5;
    const f32x4 ksc0 = *(const f32x4*)&Sl[0][tw + (lg << 2)];
    const f32x4 ksc1 = *(const f32x4*)&Sl[0][tw + 16 + (lg << 2)];
    const f32x4 kzr0 = *(const f32x4*)&Sl[1][tw + (lg << 2)];
    const f32x4 kzr1 = *(const f32x4*)&Sl[1][tw + 16 + (lg << 2)];
    const f32x4 vsc0 = *(const f32x4*)&Sl[2][tw + (lg << 2)];
    const f32x4 vsc1 = *(const f32x4*)&Sl[2][tw + 16 + (lg << 2)];
    const f32x4 vzr0 = *(const f32x4*)&Sl[3][tw + (lg << 2)];
    const f32x4 vzr1 = *(const f32x4*)&Sl[3][tw + 16 + (lg << 2)];

    // ---- QK swapped, split accumulator chains; setprio around MFMA ----
    f32x4 sA0 = (f32x4){0.f,0.f,0.f,0.f}, sA1 = (f32x4){0.f,0.f,0.f,0.f};
    f32x4 sB0 = (f32x4){0.f,0.f,0.f,0.f}, sB1 = (f32x4){0.f,0.f,0.f,0.f};
    __builtin_amdgcn_s_setprio(1);
#pragma unroll
    for (int ks = 0; ks < 2; ++ks) {
      f16x8 kfA = *(const f16x8*)
          &Klds[l15][(ks * 32 + (lg << 3)) ^ ((l15 & 7) << 3)];
      sA0 = __builtin_amdgcn_mfma_f32_16x16x32_f16(kfA, qa[ks], sA0, 0, 0, 0);
      f16x8 kfB = *(const f16x8*)
          &Klds[16 + l15][(ks * 32 + (lg << 3)) ^ ((l15 & 7) << 3)];
      sB0 = __builtin_amdgcn_mfma_f32_16x16x32_f16(kfB, qa[ks], sB0, 0, 0, 0);
    }
#pragma unroll
    for (int ks = 2; ks < 4; ++ks) {
      f16x8 kfA = *(const f16x8*)
          &Klds[l15][(ks * 32 + (lg << 3)) ^ ((l15 & 7) << 3)];
      sA1 = __builtin_amdgcn_mfma_f32_16x16x32_f16(kfA, qa[ks], sA1, 0, 0, 0);
      f16x8 kfB = *(const f16x8*)
          &Klds[16 + l15][(ks * 32 + (lg << 3)) ^ ((l15 & 7) << 3)];
      sB1 = __builtin_amdgcn_mfma_f32_16x16x32_f16(kfB, qa[ks], sB1, 0, 0, 0);
    }
    __builtin_amdgcn_s_setprio(0);
    const f32x4 scA = sA0 + sA1;
    const f32x4 scB = sB0 + sB1;

    // ---- scores (scales prefolded) ----
    float s0[4], s1[4];
#pragma unroll
    for (int j = 0; j < 4; ++j) {
      s0[j] = ksc0[j] * (scA[j] - kzr0[j] * qsum);
      s1[j] = ksc1[j] * (scB[j] - kzr1[j] * qsum);
    }

    // ---- T13 defer-max: rescale only when tile max exceeds m+THR ----
    float tm = fmaxf(fmaxf(fmaxf(s0[0], s0[1]), fmaxf(s0[2], s0[3])),
                     fmaxf(fmaxf(s1[0], s1[1]), fmaxf(s1[2], s1[3])));
    tm = fmaxf(tm, __shfl_xor(tm, 16));
    tm = fmaxf(tm, __shfl_xor(tm, 32));
    if (__any(tm > m + THR)) {             // rare after early tiles
      float nm = fmaxf(m, tm);
      float cf = exp2f(m - nm);
      m = nm;
      ell *= cf; corr *= cf;
      float cfq[4];
#pragma unroll
      for (int j = 0; j < 4; ++j) cfq[j] = __shfl(cf, (lg << 2) + j);
#pragma unroll
      for (int dt = 0; dt < 8; ++dt)
#pragma unroll
        for (int j = 0; j < 4; ++j) acc[dt][j] *= cfq[j];
    }

    // ---- P in registers (P'' = p*vs*1024, prefolded); corr on ROUNDED P'' --
    f16x8 pp;
#pragma unroll
    for (int j = 0; j < 4; ++j) {
      float pA = exp2f(s0[j] - m);
      float pB = exp2f(s1[j] - m);
      ell += pA + pB;
      _Float16 ca = (_Float16)(pA * vsc0[j]);
      _Float16 cb = (_Float16)(pB * vsc1[j]);
      corr += (float)ca * vzr0[j] + (float)cb * vzr1[j];
      pp[j]     = ca;                      // k-slot j   -> token 4lg+j
      pp[4 + j] = cb;                      // k-slot 4+j -> token 16+4lg+j
    }

    // ---- PV: acc = mfma(P, V); setprio around MFMA cluster ----
    __builtin_amdgcn_s_setprio(1);
#pragma unroll
    for (int dt = 0; dt < 8; ++dt) {
      const int swz = (dt & 3) << 3;
      f16x4 vA = *(const f16x4*)&Vlds[(dt << 4) + l15][(lg << 2) ^ swz];
      f16x4 vB = *(const f16x4*)&Vlds[(dt << 4) + l15][(16 + (lg << 2)) ^ swz];
      f16x8 vf = __builtin_shufflevector(vA, vB, 0, 1, 2, 3, 4, 5, 6, 7);
      acc[dt] = __builtin_amdgcn_mfma_f32_16x16x32_f16(pp, vf, acc[dt], 0, 0, 0);
    }
    __builtin_amdgcn_s_setprio(0);

    // ---- locked: write tile it+1 (2 computes in flight); reissue its set --
    if (it + 1 < nt) {
      if (it & 1) {
        BAR();
        WRITE(kpB, vpB);
        if (it + 3 < nt) ISSUE(kpB, vpB, it + 3);
        BAR();
      } else {
        BAR();
        WRITE(kpA, vpA);
        if (it + 3 < nt) ISSUE(kpA, vpA, it + 3);
        BAR();
      }
    }
  }

  // ---- final reductions: ell/corr across lg groups (row l15) ----
  ell += __shfl_xor(ell, 16);  ell += __shfl_xor(ell, 32);
  corr += __shfl_xor(corr, 16); corr += __shfl_xor(corr, 32);
  float corrq[4];
#pragma unroll
  for (int j = 0; j < 4; ++j) corrq[j] = __shfl(corr, (lg << 2) + j);

  const size_t pbase = ((size_t)bg * nsplit + split) * 64;
  const float inv1k = 0.0009765625f;       // 1/1024 (undo P'' scaling)
#pragma unroll
  for (int dt = 0; dt < 8; ++dt)
#pragma unroll
    for (int j = 0; j < 4; ++j) {
      int row = (wave << 4) + (lg << 2) + j;   // q-row
      int d   = (dt << 4) + l15;
      ws_acc[(pbase + row) * Dc + d] = (acc[dt][j] - corrq[j]) * inv1k;
    }
  if (lg == 0) {
    ws_m[pbase + (wave << 4) + l15] = m;
    ws_l[pbase + (wave << 4) + l15] = ell;
  }
#undef ISSUE
#undef WRITE
#undef RESTAGE
}

// ---------------------------------------------------------------------------
// Phase 2: flash-combine partials and normalize. One block per (bg,row).
// ---------------------------------------------------------------------------
__global__ __launch_bounds__(128) void attn_combine(
    const float* __restrict__ ws_acc, const float* __restrict__ ws_m,
    const float* __restrict__ ws_l, float* __restrict__ out, int nsplit)
{
  const int r   = blockIdx.x;      // 0 .. 32*64-1
  const int bg  = r >> 6;
  const int row = r & 63;
  const int d   = threadIdx.x;     // 0..127

  float M = -1e30f;
#pragma unroll 4
  for (int i = 0; i < nsplit; ++i)
    M = fmaxf(M, ws_m[((size_t)bg * nsplit + i) * 64 + row]);
  float L = 0.f, o = 0.f;
#pragma unroll 4
  for (int i = 0; i < nsplit; ++i) {
    size_t pb = ((size_t)bg * nsplit + i) * 64 + row;
    float w = exp2f(ws_m[pb] - M);
    L += ws_l[pb] * w;
    o += ws_acc[pb * Dc + d] * w;
  }
  const int b = bg >> 3, g = bg & 7;
  const int rep = row >> 4, qq = row & 15;
  out[(((size_t)(b * Hc + g * NREPc + rep)) * QLc + qq) * Dc + d] = o / L;
}

extern "C" void kernel_launch(void* const* d_in, const int* in_sizes, int n_in,
                              void* d_out, int out_size, void* d_ws,
                              size_t ws_size, hipStream_t stream) {
  const float* q   = (const float*)d_in[0];
  const int*   kc  = (const int*)d_in[1];   // int8 values promoted to int32
  const int*   vc  = (const int*)d_in[2];
  const float* ksc = (const float*)d_in[3];
  const float* kzr = (const float*)d_in[4];
  const float* vsc = (const float*)d_in[5];
  const float* vzr = (const float*)d_in[6];
  float* out = (float*)d_out;

  int nsplit = 32;                         // 1024 blocks = 4/CU (residency
  while (nsplit > 1) {                     // cap) -> no sequential rounds
    size_t need = (size_t)32 * nsplit * 64 * (Dc + 2) * sizeof(float);
    if (need <= ws_size) break;
    nsplit >>= 1;
  }
  float* ws_acc = (float*)d_ws;                             // [32,ns,64,128]
  float* ws_m   = ws_acc + (size_t)32 * nsplit * 64 * Dc;   // [32,ns,64]
  float* ws_l   = ws_m   + (size_t)32 * nsplit * 64;        // [32,ns,64]

  attn_partial<<<dim3(32 * nsplit), dim3(256), 0, stream>>>(
      q, kc, vc, ksc, kzr, vsc, vzr, ws_acc, ws_m, ws_l, nsplit);
  attn_combine<<<dim3(32 * 64), dim3(128), 0, stream>>>(
      ws_acc, ws_m, ws_l, out, nsplit);
}